// Round 6
// baseline (208.700 us; speedup 1.0000x reference)
//
#include <hip/hip_runtime.h>

// YOLO loss: S=14, B=2, C=20, N_CH=30, batch=4096
// pred, target: (4096, 14, 14, 30) float32. Output: scalar float32.
//
// R11 = R10 with the compile fix: __builtin_nontemporal_load requires a
// clang ext_vector_type pointer (HIP_vector_type float4 is a struct and is
// rejected). Theory under test (unchanged): 2.6 TB/s plateau is invariant
// to mechanism/occupancy/pipelining (R0/R2/R4/R5/R7/R9); FETCH=94MB of a
// 193MB read => half the stream is L3-hit-served; hypothesis is the L3
// lookup/hit pipe caps ~2.6 TB/s. nt loads (no-allocate/evict-first) keep
// the stream HBM-resident at copy rate.
//
// Structure = R7 (passed, absmax 0): coalesced float4 TCP-return stream,
// box channels scattered to 10.75 KiB LDS, class loss summed masklessly
// per-float4 and masked after the barrier via in-stream mtab.
// R7's 52MB spill bug root-caused: __launch_bounds__(128,7) forced VGPR=40
// -> scratch. Clamp removed; VGPRs float (no spill).

#define SDIM 14
#define NCH  30
#define BATCH 4096
#define NCELLS (BATCH * SDIM * SDIM)      // 802816
#define TILE_CELLS 128
#define NTILES (NCELLS / TILE_CELLS)      // 6272, exact
#define TPB 2                             // tiles per block
#define NBLOCKS (NTILES / TPB)            // 3136
#define THREADS 128
#define TILE_F4 (TILE_CELLS * NCH / 4)    // 960 float4 per tensor per tile
#define L_COORD 5.0f
#define L_NOOBJ 0.5f

typedef float floatx4 __attribute__((ext_vector_type(4)));

__global__ __launch_bounds__(THREADS) void yolo_loss_stage1(
    const float* __restrict__ pred,
    const float* __restrict__ tgt,
    float* __restrict__ partial)
{
    // Box channels only: 128 cells x 10 ch x 4 B x 2 tensors = 10240 B.
    __shared__ __align__(16) float pbox[TILE_CELLS * 10];
    __shared__ __align__(16) float tbox[TILE_CELLS * 10];
    __shared__ float mtab[TILE_CELLS];    // m(cell), written in-stream each tile
    __shared__ float wsum[2];

    const int tid = threadIdx.x;
    const size_t tile0 = (size_t)blockIdx.x * TPB;

    float acc = 0.0f;

    for (int it = 0; it < TPB; ++it) {
        const size_t base = (tile0 + it) * (size_t)(TILE_CELLS * NCH);
        const floatx4* gp4 = (const floatx4*)(pred + base);
        const floatx4* gt4 = (const floatx4*)(tgt + base);

        // ---- P2: lane-contiguous NONTEMPORAL float4 stream of BOTH tensors.
        // float4 #k covers flat floats 4k..4k+3; cell = f/30, ch = f%30.
        // k = 15q + rm  ->  cell0 = 2q + (rm>=8),  r = 4*rm - 30*(rm>=8).
        // Only rm==7 (r==28) straddles a cell; wrapped elements are ch 0/1
        // (box) of cell0+1, so class elements ALWAYS belong to cell0.
        float sj[8];
        #pragma unroll
        for (int j = 0; j < 8; ++j) sj[j] = 0.0f;

        #pragma unroll
        for (int j = 0; j < 8; ++j) {
            int k = j * THREADS + tid;
            if (k < TILE_F4) {                      // j==7: only tid<64 active
                floatx4 p4  = __builtin_nontemporal_load(gp4 + k);
                floatx4 t4v = __builtin_nontemporal_load(gt4 + k);
                int q  = k / 15;
                int rm = k - q * 15;
                int hi = (rm >= 8) ? 1 : 0;
                int cell0 = 2 * q + hi;
                int r = 4 * rm - 30 * hi;           // even, 0..28

                // Mask owners (one unique writer per cell):
                // even cell ch4 = rm1 elem .x ; odd cell ch4 = rm8 elem .z
                if (rm == 1) mtab[cell0] = (t4v.x > 0.0f) ? 1.0f : 0.0f;
                if (rm == 8) mtab[cell0] = (t4v.z > 0.0f) ? 1.0f : 0.0f;

                float pe[4] = {p4.x, p4.y, p4.z, p4.w};
                float te[4] = {t4v.x, t4v.y, t4v.z, t4v.w};
                float s = 0.0f;
                #pragma unroll
                for (int e = 0; e < 4; ++e) {
                    int ch = r + e;
                    int cell = cell0;
                    if (ch >= NCH) { ch -= NCH; cell += 1; }   // wrap -> box ch 0/1
                    if (ch < 10) {
                        pbox[cell * 10 + ch] = pe[e];
                        tbox[cell * 10 + ch] = te[e];
                    } else {
                        float d = pe[e] - te[e];
                        s = fmaf(d, d, s);          // maskless class partial
                    }
                }
                sj[j] = s;
            }
        }
        __syncthreads();   // scatter + mask table complete

        // ---- P2b: deferred class loss, mask applied from mtab.
        #pragma unroll
        for (int j = 0; j < 8; ++j) {
            int k = j * THREADS + tid;
            if (k < TILE_F4) {
                int q  = k / 15;
                int rm = k - q * 15;
                int cell0 = 2 * q + ((rm >= 8) ? 1 : 0);
                acc = fmaf(mtab[cell0], sj[j], acc);
            }
        }

        // ---- P3: per-cell box/obj/noobj math; thread tid owns cell tid.
        {
            float pv[10], tv[10];
            const float2* lp = (const float2*)(pbox + tid * 10);  // 8B-aligned
            const float2* lt = (const float2*)(tbox + tid * 10);
            #pragma unroll
            for (int i = 0; i < 5; ++i) {
                float2 a = lp[i]; pv[2*i] = a.x; pv[2*i+1] = a.y;
                float2 b = lt[i]; tv[2*i] = b.x; tv[2*i+1] = b.y;
            }

            const float invS = 1.0f / (float)SDIM;
            float m  = (tv[4] > 0.0f) ? 1.0f : 0.0f;
            float nm = 1.0f - m;

            // target box 0 -> xyxy
            float tcx = tv[0] * invS, tcy = tv[1] * invS;
            float tw  = tv[2],        th  = tv[3];
            float tx1 = tcx - 0.5f * tw, ty1 = tcy - 0.5f * th;
            float tx2 = tcx + 0.5f * tw, ty2 = tcy + 0.5f * th;
            float ta  = (tx2 - tx1) * (ty2 - ty1);

            float iou0, iou1;
            {
                float cx = pv[0] * invS, cy = pv[1] * invS;
                float x1 = cx - 0.5f * pv[2], y1 = cy - 0.5f * pv[3];
                float x2 = cx + 0.5f * pv[2], y2 = cy + 0.5f * pv[3];
                float iw = fmaxf(fminf(x2, tx2) - fmaxf(x1, tx1), 0.0f);
                float ih = fmaxf(fminf(y2, ty2) - fmaxf(y1, ty1), 0.0f);
                float inter = iw * ih;
                float pa = (x2 - x1) * (y2 - y1);
                iou0 = inter / (pa + ta - inter);
            }
            {
                float cx = pv[5] * invS, cy = pv[6] * invS;
                float x1 = cx - 0.5f * pv[7], y1 = cy - 0.5f * pv[8];
                float x2 = cx + 0.5f * pv[7], y2 = cy + 0.5f * pv[8];
                float iw = fmaxf(fminf(x2, tx2) - fmaxf(x1, tx1), 0.0f);
                float ih = fmaxf(fminf(y2, ty2) - fmaxf(y1, ty1), 0.0f);
                float inter = iw * ih;
                float pa = (x2 - x1) * (y2 - y1);
                iou1 = inter / (pa + ta - inter);
            }

            // argmax (first-wins tie = jnp.argmax); scalar selects only,
            // NO runtime-indexed arrays (R7 scratch lesson).
            bool  sel     = (iou1 > iou0);
            float max_iou = sel ? iou1 : iou0;
            float rp0 = sel ? pv[5] : pv[0];
            float rp1 = sel ? pv[6] : pv[1];
            float rp2 = sel ? pv[7] : pv[2];
            float rp3 = sel ? pv[8] : pv[3];
            float rp4 = sel ? pv[9] : pv[4];
            float rt0 = sel ? tv[5] : tv[0];
            float rt1 = sel ? tv[6] : tv[1];
            float rt2 = sel ? tv[7] : tv[2];
            float rt3 = sel ? tv[8] : tv[3];

            float dx = rp0 - rt0, dy = rp1 - rt1;
            float dxy = dx * dx + dy * dy;
            float sw = sqrtf(rp2) - sqrtf(rt2);
            float sh = sqrtf(rp3) - sqrtf(rt3);
            float dwh = sw * sw + sh * sh;
            float dob = (rp4 - max_iou) * (rp4 - max_iou);
            float d4 = pv[4] - tv[4];
            float d9 = pv[9] - tv[9];
            float dnoobj = d4 * d4 + d9 * d9;

            acc += m * (L_COORD * (dxy + dwh) + dob) + nm * L_NOOBJ * dnoobj;
        }

        __syncthreads();   // all LDS reads done before next tile's writes
    }

    // ---- Reduction: wave shuffle -> wsum -> one partial per block
    #pragma unroll
    for (int off = 32; off > 0; off >>= 1)
        acc += __shfl_down(acc, off, 64);

    const int w = tid >> 6, lane = tid & 63;
    if (lane == 0) wsum[w] = acc;
    __syncthreads();
    if (tid == 0) partial[blockIdx.x] = wsum[0] + wsum[1];
}

__global__ __launch_bounds__(256) void yolo_loss_stage2(
    const float* __restrict__ partial,
    float* __restrict__ out)
{
    const int tid = threadIdx.x;
    float s = 0.0f;
    for (int i = tid; i < NBLOCKS; i += 256) s += partial[i];

    #pragma unroll
    for (int off = 32; off > 0; off >>= 1)
        s += __shfl_down(s, off, 64);

    __shared__ float wsum[4];
    int lane = tid & 63;
    int wid  = tid >> 6;
    if (lane == 0) wsum[wid] = s;
    __syncthreads();
    if (tid == 0) {
        out[0] = (wsum[0] + wsum[1] + wsum[2] + wsum[3]) * (1.0f / (float)BATCH);
    }
}

extern "C" void kernel_launch(void* const* d_in, const int* in_sizes, int n_in,
                              void* d_out, int out_size, void* d_ws, size_t ws_size,
                              hipStream_t stream)
{
    const float* pred = (const float*)d_in[0];
    const float* tgt  = (const float*)d_in[1];
    float* out        = (float*)d_out;
    float* partial    = (float*)d_ws;   // 3136 floats = 12.5 KB

    hipLaunchKernelGGL(yolo_loss_stage1, dim3(NBLOCKS), dim3(THREADS), 0, stream,
                       pred, tgt, partial);
    hipLaunchKernelGGL(yolo_loss_stage2, dim3(1), dim3(256), 0, stream,
                       partial, out);
}